// Round 4
// baseline (11815.810 us; speedup 1.0000x reference)
//
#include <hip/hip_runtime.h>
#include <cstdint>
#include <cstddef>

#define B_    64
#define NP1   1025
#define N_    1024
#define D_    256
#define DP1   257
#define L_    4
#define H_    4
#define NPAD  1088   // m dimension (KT width), 34 chunks of 32
#define NROWS 1152   // Zb row allocation: 9 blocks x 128 n-rows
#define IPAD  272    // padded output feature dim (257 -> 17*16)
#define NCH   (NPAD / 32)

typedef __bf16 bf16;
typedef bf16 bf16x8 __attribute__((ext_vector_type(8)));
typedef float f32x4 __attribute__((ext_vector_type(4)));

__device__ __forceinline__ f32x4 mfma16(bf16x8 a, bf16x8 b, f32x4 c) {
    return __builtin_amdgcn_mfma_f32_16x16x32_bf16(a, b, c, 0, 0, 0);
}

__device__ __forceinline__ void async16(const void* g, void* l) {
    __builtin_amdgcn_global_load_lds(
        (const __attribute__((address_space(1))) void*)g,
        (__attribute__((address_space(3))) void*)l, 16, 0, 0);
}

// ---------------------------------------------------------------------------
__global__ void k_prep_pq(const float* __restrict__ ap,
                          bf16* __restrict__ Pb, bf16* __restrict__ Qt) {
    int idx = blockIdx.x * 256 + threadIdx.x;   // L*H*D*D = 1048576
    int j  = idx & 255;
    int i  = (idx >> 8) & 255;
    int lh = idx >> 16;
    const float* base = ap + (size_t)lh * 2 * D_ * D_;
    float p = base[i * D_ + j];
    float q = base[D_ * D_ + i * D_ + j];
    Pb[((size_t)lh * D_ + i) * D_ + j] = (bf16)p;
    Qt[((size_t)lh * D_ + j) * D_ + i] = (bf16)q;   // Qt[j][i] = Q[i][j]
}

// ---------------------------------------------------------------------------
__global__ void k_z2b(const float* __restrict__ Z, bf16* __restrict__ Zb) {
    int n = blockIdx.x, b = blockIdx.y, i = threadIdx.x;
    float v = 0.f;
    if (n < NP1) v = Z[((size_t)b * NP1 + n) * DP1 + i];
    Zb[((size_t)b * NROWS + n) * D_ + i] = (bf16)v;
}

// ---------------------------------------------------------------------------
// KT[b,h,i,m] = sum_j P[l,h,i,j] * Zb[b,m,j], zero for m>=1024
// ---------------------------------------------------------------------------
__global__ __launch_bounds__(256) void k_kt(const bf16* __restrict__ Zb,
                                            const bf16* __restrict__ Pb,
                                            bf16* __restrict__ KT, int layer) {
    int tid = threadIdx.x;
    int wave = tid >> 6, lane = tid & 63, quad = lane >> 4, l16 = lane & 15;
    int mt = blockIdx.x, it = blockIdx.y, bh = blockIdx.z;
    int b = bh >> 2, h = bh & 3;
    int i0 = it * 64 + wave * 16;
    int m0 = mt * 64;

    const bf16* Prow = Pb + ((size_t)(layer * H_ + h) * D_ + (i0 + l16)) * D_ + quad * 8;
    bf16x8 a[8];
#pragma unroll
    for (int k = 0; k < 8; k++) a[k] = *(const bf16x8*)(Prow + k * 32);

    const bf16* Zbb = Zb + (size_t)b * NROWS * D_;
    f32x4 c[4];
#pragma unroll
    for (int s = 0; s < 4; s++) c[s] = (f32x4){0.f, 0.f, 0.f, 0.f};

#pragma unroll
    for (int s = 0; s < 4; s++) {
        const bf16* brow = Zbb + (size_t)(m0 + s * 16 + l16) * D_ + quad * 8;
#pragma unroll
        for (int k = 0; k < 8; k++)
            c[s] = mfma16(a[k], *(const bf16x8*)(brow + k * 32), c[s]);
    }

    bf16* KTbh = KT + (size_t)(b * H_ + h) * IPAD * NPAD;
#pragma unroll
    for (int s = 0; s < 4; s++) {
        int m = m0 + s * 16 + l16;
#pragma unroll
        for (int r = 0; r < 4; r++) {
            float v = (m < N_) ? c[s][r] : 0.f;
            KTbh[(size_t)(i0 + quad * 4 + r) * NPAD + m] = (bf16)v;
        }
    }
}

// ---------------------------------------------------------------------------
__global__ void k_kt_extra(const float* __restrict__ Z, bf16* __restrict__ KT) {
    int m = blockIdx.x * 256 + threadIdx.x;
    int b = blockIdx.y;
    if (m >= NPAD) return;
    float v = (m < N_) ? Z[((size_t)b * NP1 + m) * DP1 + D_] : 0.f;
    bf16 bv = (bf16)v;
#pragma unroll
    for (int h = 0; h < H_; h++) {
        bf16* row = KT + ((size_t)(b * H_ + h) * IPAD + D_) * NPAD + m;
        row[0] = bv;
#pragma unroll
        for (int r = 1; r < 16; r++) row[(size_t)r * NPAD] = (bf16)0.f;
    }
}

// ---------------------------------------------------------------------------
// Fused flash attention v4: KT read direct from global (register-pipelined,
// cacheline-aligned), only Zb staged in LDS (16 KB/iter) -> LDS 42.7 KB,
// 2-3 blocks/CU. XCD-swizzled grid. Block = 128 n x 272 i, 4 waves x 32 n.
// ---------------------------------------------------------------------------
__global__ __launch_bounds__(256, 2) void k_attn(const bf16* __restrict__ Zb,
                                                 const bf16* __restrict__ KT,
                                                 const bf16* __restrict__ Qt,
                                                 float* __restrict__ Z, int layer) {
    __shared__ bf16 zbS[2][32][256];   // XOR-swizzled: f(r) = r&7
    __shared__ bf16 sl[4][32][40];

    const int tid  = threadIdx.x;
    const int wave = tid >> 6, lane = tid & 63;
    const int quad = lane >> 4, l16 = lane & 15;

    // XCD swizzle: all 9 n-blocks of a given b on the same XCD (id & 7)
    const int id  = blockIdx.x;
    const int xcd = id & 7, kk = id >> 3;
    const int b   = xcd + 8 * (kk / 9);
    const int bx  = kk % 9;
    const int n0w = bx * 128 + wave * 32;

    const bf16* Zbb = Zb + (size_t)b * NROWS * D_;

    const int zrow  = wave * 2 + (lane >> 5);
    const int zscol = ((lane & 31) ^ (zrow & 7)) * 8;
    const int xs    = l16 & 7;

    f32x4 acc[2][17];
#pragma unroll
    for (int ns = 0; ns < 2; ns++)
#pragma unroll
        for (int it = 0; it < 17; it++) acc[ns][it] = (f32x4){0.f, 0.f, 0.f, 0.f};

    auto stage = [&](int mc_, int p_) {
        int m0 = mc_ * 32;
        const bf16* zsrc = Zbb + (size_t)(m0 + zrow) * D_ + zscol;
#pragma unroll
        for (int t = 0; t < 4; t++)
            async16(zsrc + (size_t)t * 8 * D_, &zbS[p_][t * 8 + wave * 2][0]);
    };

    for (int h = 0; h < H_; h++) {
        const bf16* Qth  = Qt + (size_t)(layer * H_ + h) * D_ * D_;
        const bf16* KTbh = KT + (size_t)(b * H_ + h) * IPAD * NPAD;

        // ---- phase 1: ZQ -> zqa A-frags ----
        bf16x8 zqa[2][8];
#pragma unroll
        for (int ns = 0; ns < 2; ns++) {
            bf16x8 azc[8];
            const bf16* arow = Zbb + (size_t)(n0w + ns * 16 + l16) * D_ + quad * 8;
#pragma unroll
            for (int kc = 0; kc < 8; kc++)
                azc[kc] = *(const bf16x8*)(arow + kc * 32);
#pragma unroll 2
            for (int jc = 0; jc < 8; jc++) {
                f32x4 c0 = (f32x4){0.f, 0.f, 0.f, 0.f};
                f32x4 c1 = (f32x4){0.f, 0.f, 0.f, 0.f};
#pragma unroll
                for (int kc = 0; kc < 8; kc++) {
                    const bf16* qb = Qth + (size_t)(jc * 32 + l16) * D_ + kc * 32 + quad * 8;
                    c0 = mfma16(azc[kc], *(const bf16x8*)(qb), c0);
                    c1 = mfma16(azc[kc], *(const bf16x8*)(qb + 16 * D_), c1);
                }
#pragma unroll
                for (int r = 0; r < 4; r++) {
                    sl[wave][ns * 16 + quad * 4 + r][l16]      = (bf16)c0[r];
                    sl[wave][ns * 16 + quad * 4 + r][16 + l16] = (bf16)c1[r];
                }
                zqa[ns][jc] = *(const bf16x8*)(&sl[wave][ns * 16 + l16][quad * 8]);
            }
        }

        if (h == 0) {
            stage(0, 0);
            __syncthreads();
        }
        // h>0: chunk 0 staged during previous head's last iteration

        for (int mc = 0; mc < NCH; mc++) {
            int p = mc & 1;
            if (!(h == H_ - 1 && mc == NCH - 1))
                stage((mc + 1) % NCH, p ^ 1);    // Zb is head-independent

            int m0 = mc * 32;

            // ---- S = relu(ZQ . Zb_chunk^T) ----
            f32x4 s[2][2];
#pragma unroll
            for (int ns = 0; ns < 2; ns++)
#pragma unroll
                for (int mt = 0; mt < 2; mt++) s[ns][mt] = (f32x4){0.f, 0.f, 0.f, 0.f};
#pragma unroll
            for (int mt = 0; mt < 2; mt++) {
                const bf16* zr = &zbS[p][mt * 16 + l16][0];
#pragma unroll
                for (int kc = 0; kc < 8; kc++) {
                    bf16x8 bz = *(const bf16x8*)(zr + (((kc * 4 + quad) ^ xs) * 8));
                    s[0][mt] = mfma16(zqa[0][kc], bz, s[0][mt]);
                    s[1][mt] = mfma16(zqa[1][kc], bz, s[1][mt]);
                }
            }
#pragma unroll
            for (int ns = 0; ns < 2; ns++)
#pragma unroll
                for (int mt = 0; mt < 2; mt++)
#pragma unroll
                    for (int r = 0; r < 4; r++) {
                        float v = s[ns][mt][r];
                        sl[wave][ns * 16 + quad * 4 + r][mt * 16 + l16] =
                            (bf16)(v > 0.f ? v : 0.f);
                    }
            bf16x8 a2[2];
#pragma unroll
            for (int ns = 0; ns < 2; ns++)
                a2[ns] = *(const bf16x8*)(&sl[wave][ns * 16 + l16][quad * 8]);

            // ---- acc += S . KT_chunk^T, B-frags direct from global ----
            // lane addr: row (it*16+l16), cols m0+quad*8 .. +8 — all 4 quads
            // of one row share a single 64B cacheline.
            const bf16* kcol = KTbh + (size_t)l16 * NPAD + m0 + quad * 8;
            {
                bf16x8 bk[9];
#pragma unroll
                for (int it = 0; it < 9; it++)
                    bk[it] = *(const bf16x8*)(kcol + (size_t)(it * 16) * NPAD);
#pragma unroll
                for (int it = 0; it < 9; it++) {
                    acc[0][it] = mfma16(a2[0], bk[it], acc[0][it]);
                    acc[1][it] = mfma16(a2[1], bk[it], acc[1][it]);
                }
            }
            {
                bf16x8 bk[8];
#pragma unroll
                for (int it = 0; it < 8; it++)
                    bk[it] = *(const bf16x8*)(kcol + (size_t)((it + 9) * 16) * NPAD);
#pragma unroll
                for (int it = 0; it < 8; it++) {
                    acc[0][it + 9] = mfma16(a2[0], bk[it], acc[0][it + 9]);
                    acc[1][it + 9] = mfma16(a2[1], bk[it], acc[1][it + 9]);
                }
            }
            __syncthreads();
        }
    }

    // ---- epilogue: Z += acc / N ----
    const float inv = 1.0f / (float)N_;
#pragma unroll
    for (int ns = 0; ns < 2; ns++)
#pragma unroll
        for (int it = 0; it < 17; it++)
#pragma unroll
            for (int r = 0; r < 4; r++) {
                int n = n0w + ns * 16 + quad * 4 + r;
                int i = it * 16 + l16;
                if (n < NP1 && i < DP1)
                    Z[((size_t)b * NP1 + n) * DP1 + i] += acc[ns][it][r] * inv;
            }
}

// ---------------------------------------------------------------------------
extern "C" void kernel_launch(void* const* d_in, const int* in_sizes, int n_in,
                              void* d_out, int out_size, void* d_ws, size_t ws_size,
                              hipStream_t stream) {
    const float* Zin = (const float*)d_in[0];
    const float* ap  = (const float*)d_in[1];
    float* Z = (float*)d_out;

    char* ws = (char*)d_ws;
    const size_t sz_Zb = (size_t)B_ * NROWS * D_ * sizeof(bf16);
    const size_t sz_KT = (size_t)B_ * H_ * IPAD * NPAD * sizeof(bf16);
    const size_t sz_P  = (size_t)L_ * H_ * D_ * D_ * sizeof(bf16);
    bf16* Zb = (bf16*)ws;
    bf16* KT = (bf16*)(ws + sz_Zb);
    bf16* Pb = (bf16*)(ws + sz_Zb + sz_KT);
    bf16* Qt = (bf16*)(ws + sz_Zb + sz_KT + sz_P);

    hipMemcpyAsync(Z, Zin, (size_t)B_ * NP1 * DP1 * sizeof(float),
                   hipMemcpyDeviceToDevice, stream);

    k_prep_pq<<<dim3((L_ * H_ * D_ * D_) / 256), 256, 0, stream>>>(ap, Pb, Qt);

    for (int l = 0; l < L_; l++) {
        k_z2b<<<dim3(NROWS, B_), 256, 0, stream>>>(Z, Zb);
        k_kt<<<dim3(NPAD / 64, D_ / 64, B_ * H_), 256, 0, stream>>>(Zb, Pb, KT, l);
        k_kt_extra<<<dim3((NPAD + 255) / 256, B_), 256, 0, stream>>>(Z, KT);
        k_attn<<<dim3(9 * B_), 256, 0, stream>>>(Zb, KT, Qt, Z, l);
    }
}

// Round 5
// 7611.762 us; speedup vs baseline: 1.5523x; 1.5523x over previous
//
#include <hip/hip_runtime.h>
#include <cstdint>
#include <cstddef>

#define B_    64
#define NP1   1025
#define N_    1024
#define D_    256
#define DP1   257
#define L_    4
#define H_    4
#define NPAD  1088   // m dimension (KT width), 34 chunks of 32
#define NROWS 1152   // Zb row allocation: 9 blocks x 128 n-rows
#define IPAD  272    // padded output feature dim (257 -> 17*16)
#define NCH   (NPAD / 32)

typedef __bf16 bf16;
typedef bf16 bf16x4 __attribute__((ext_vector_type(4)));
typedef bf16 bf16x8 __attribute__((ext_vector_type(8)));
typedef float f32x4 __attribute__((ext_vector_type(4)));

__device__ __forceinline__ f32x4 mfma16(bf16x8 a, bf16x8 b, f32x4 c) {
    return __builtin_amdgcn_mfma_f32_16x16x32_bf16(a, b, c, 0, 0, 0);
}

__device__ __forceinline__ void async16(const void* g, void* l) {
    __builtin_amdgcn_global_load_lds(
        (const __attribute__((address_space(1))) void*)g,
        (__attribute__((address_space(3))) void*)l, 16, 0, 0);
}

// ---------------------------------------------------------------------------
__global__ void k_prep_pq(const float* __restrict__ ap,
                          bf16* __restrict__ Pb, bf16* __restrict__ Qt) {
    int idx = blockIdx.x * 256 + threadIdx.x;   // L*H*D*D = 1048576
    int j  = idx & 255;
    int i  = (idx >> 8) & 255;
    int lh = idx >> 16;
    const float* base = ap + (size_t)lh * 2 * D_ * D_;
    float p = base[i * D_ + j];
    float q = base[D_ * D_ + i * D_ + j];
    Pb[((size_t)lh * D_ + i) * D_ + j] = (bf16)p;
    Qt[((size_t)lh * D_ + j) * D_ + i] = (bf16)q;   // Qt[j][i] = Q[i][j]
}

// ---------------------------------------------------------------------------
__global__ void k_z2b(const float* __restrict__ Z, bf16* __restrict__ Zb) {
    int n = blockIdx.x, b = blockIdx.y, i = threadIdx.x;
    float v = 0.f;
    if (n < NP1) v = Z[((size_t)b * NP1 + n) * DP1 + i];
    Zb[((size_t)b * NROWS + n) * D_ + i] = (bf16)v;
}

// ---------------------------------------------------------------------------
// KT[b,h,i,m] = sum_j P[l,h,i,j] * Zb[b,m,j], zero for m>=1024
// ---------------------------------------------------------------------------
__global__ __launch_bounds__(256) void k_kt(const bf16* __restrict__ Zb,
                                            const bf16* __restrict__ Pb,
                                            bf16* __restrict__ KT, int layer) {
    int tid = threadIdx.x;
    int wave = tid >> 6, lane = tid & 63, quad = lane >> 4, l16 = lane & 15;
    int mt = blockIdx.x, it = blockIdx.y, bh = blockIdx.z;
    int b = bh >> 2, h = bh & 3;
    int i0 = it * 64 + wave * 16;
    int m0 = mt * 64;

    const bf16* Prow = Pb + ((size_t)(layer * H_ + h) * D_ + (i0 + l16)) * D_ + quad * 8;
    bf16x8 a[8];
#pragma unroll
    for (int k = 0; k < 8; k++) a[k] = *(const bf16x8*)(Prow + k * 32);

    const bf16* Zbb = Zb + (size_t)b * NROWS * D_;
    f32x4 c[4];
#pragma unroll
    for (int s = 0; s < 4; s++) c[s] = (f32x4){0.f, 0.f, 0.f, 0.f};

#pragma unroll
    for (int s = 0; s < 4; s++) {
        const bf16* brow = Zbb + (size_t)(m0 + s * 16 + l16) * D_ + quad * 8;
#pragma unroll
        for (int k = 0; k < 8; k++)
            c[s] = mfma16(a[k], *(const bf16x8*)(brow + k * 32), c[s]);
    }

    bf16* KTbh = KT + (size_t)(b * H_ + h) * IPAD * NPAD;
#pragma unroll
    for (int s = 0; s < 4; s++) {
        int m = m0 + s * 16 + l16;
#pragma unroll
        for (int r = 0; r < 4; r++) {
            float v = (m < N_) ? c[s][r] : 0.f;
            KTbh[(size_t)(i0 + quad * 4 + r) * NPAD + m] = (bf16)v;
        }
    }
}

// ---------------------------------------------------------------------------
// per-layer: KT row 256 = Z[b,m,256] (masked)
__global__ void k_kt_extra(const float* __restrict__ Z, bf16* __restrict__ KT) {
    int m = blockIdx.x * 256 + threadIdx.x;
    int b = blockIdx.y;
    if (m >= NPAD) return;
    float v = (m < N_) ? Z[((size_t)b * NP1 + m) * DP1 + D_] : 0.f;
    bf16 bv = (bf16)v;
#pragma unroll
    for (int h = 0; h < H_; h++)
        KT[((size_t)(b * H_ + h) * IPAD + D_) * NPAD + m] = bv;
}

// once per launch: KT rows 257..271 = 0 (layer-invariant)
__global__ void k_kt_pad(bf16* __restrict__ KT) {
    int m = blockIdx.x * 256 + threadIdx.x;
    int bh = blockIdx.y;
    if (m >= NPAD) return;
    bf16* row = KT + ((size_t)bh * IPAD + D_ + 1) * NPAD + m;
#pragma unroll
    for (int r = 0; r < 15; r++) row[(size_t)r * NPAD] = (bf16)0.f;
}

// ---------------------------------------------------------------------------
// Fused flash attention v5: R3 structure (dbuf LDS staging of Zb+KT) with
// transposed S/ZQ MFMAs (packed b64 sl writes, b128 A-frag reads) and a
// register diet to reach 2 waves/SIMD (launch_bounds 256,2).
// Block = 128 n x 272 i, 4 waves x 32 n.
// ---------------------------------------------------------------------------
__global__ __launch_bounds__(256, 2) void k_attn(const bf16* __restrict__ Zb,
                                                 const bf16* __restrict__ KT,
                                                 const bf16* __restrict__ Qt,
                                                 float* __restrict__ Z, int layer) {
    __shared__ bf16 zbS[2][32][256];   // XOR-swizzled: f(r) = r&7
    __shared__ bf16 ktS[2][IPAD][32];  // f(r) = (r>>1)&3
    __shared__ bf16 sl[4][32][40];     // per-wave roundtrip scratch

    const int tid  = threadIdx.x;
    const int wave = tid >> 6, lane = tid & 63;
    const int quad = lane >> 4, l16 = lane & 15;

    // XCD swizzle: all 9 n-blocks of a given b on the same XCD (id & 7)
    const int id  = blockIdx.x;
    const int xcd = id & 7, kk = id >> 3;
    const int b   = xcd + 8 * (kk / 9);
    const int bx  = kk % 9;
    const int n0w = bx * 128 + wave * 32;

    const bf16* Zbb = Zb + (size_t)b * NROWS * D_;

    const int zrow  = wave * 2 + (lane >> 5);
    const int zscol = ((lane & 31) ^ (zrow & 7)) * 8;
    const int krow  = wave * 16 + (lane >> 2);
    const int kscol = ((lane & 3) ^ ((lane >> 3) & 3)) * 8;
    const int xs    = l16 & 7;
    const int kf    = (l16 >> 1) & 3;

    f32x4 acc[2][17];
#pragma unroll
    for (int ns = 0; ns < 2; ns++)
#pragma unroll
        for (int it = 0; it < 17; it++) acc[ns][it] = (f32x4){0.f, 0.f, 0.f, 0.f};

    auto stage = [&](int mc_, int p_, const bf16* ktbase) {
        int m0 = mc_ * 32;
        const bf16* zsrc = Zbb + (size_t)(m0 + zrow) * D_ + zscol;
#pragma unroll
        for (int t = 0; t < 4; t++)
            async16(zsrc + (size_t)t * 8 * D_, &zbS[p_][t * 8 + wave * 2][0]);
        const bf16* ksrc = ktbase + (size_t)krow * NPAD + m0 + kscol;
#pragma unroll
        for (int t = 0; t < 4; t++)
            async16(ksrc + (size_t)t * 64 * NPAD, &ktS[p_][t * 64 + wave * 16][0]);
        if (wave == 0)
            async16(ksrc + (size_t)256 * NPAD, &ktS[p_][256][0]);
    };

    for (int h = 0; h < H_; h++) {
        const bf16* Qth  = Qt + (size_t)(layer * H_ + h) * D_ * D_;
        const bf16* KTbh = KT + (size_t)(b * H_ + h) * IPAD * NPAD;

        // ---- phase 1: ZQ^T -> zqa frags (b64-packed roundtrip) ----
        // D[j][n] = mfma(A=Qt rows j, B=Zb rows n): lane holds
        // ZQ[n=l16(+16ns)][j = jc*32 + jt*16 + quad*4 + r]  -> packed b64
        bf16x8 zqa[2][8];
#pragma unroll 2
        for (int jc = 0; jc < 8; jc++) {
            f32x4 c00 = (f32x4){0.f,0.f,0.f,0.f}, c01 = c00, c10 = c00, c11 = c00;
#pragma unroll
            for (int kc = 0; kc < 8; kc++) {
                const bf16* qb = Qth + (size_t)(jc * 32 + l16) * D_ + kc * 32 + quad * 8;
                const bf16* az = Zbb + (size_t)(n0w + l16) * D_ + kc * 32 + quad * 8;
                bf16x8 q0 = *(const bf16x8*)(qb);
                bf16x8 q1 = *(const bf16x8*)(qb + 16 * D_);
                bf16x8 a0 = *(const bf16x8*)(az);            // L1-hot after kc pass 1
                bf16x8 a1 = *(const bf16x8*)(az + 16 * D_);
                c00 = mfma16(q0, a0, c00);
                c01 = mfma16(q0, a1, c01);
                c10 = mfma16(q1, a0, c10);
                c11 = mfma16(q1, a1, c11);
            }
            f32x4 cv[2][2] = {{c00, c01}, {c10, c11}};
#pragma unroll
            for (int jt = 0; jt < 2; jt++)
#pragma unroll
                for (int ns = 0; ns < 2; ns++) {
                    bf16x4 pk;
#pragma unroll
                    for (int r = 0; r < 4; r++) pk[r] = (bf16)cv[jt][ns][r];
                    *(bf16x4*)(&sl[wave][ns * 16 + l16][jt * 16 + quad * 4]) = pk;
                }
#pragma unroll
            for (int ns = 0; ns < 2; ns++)
                zqa[ns][jc] = *(const bf16x8*)(&sl[wave][ns * 16 + l16][quad * 8]);
        }

        if (h == 0) {
            stage(0, 0, KTbh);
            __syncthreads();
        }
        // h>0: chunk 0 staged during previous head's last iteration

        for (int mc = 0; mc < NCH; mc++) {
            int p = mc & 1;
            if (mc + 1 < NCH)
                stage(mc + 1, p ^ 1, KTbh);
            else if (h + 1 < H_)
                stage(0, p ^ 1, KTbh + (size_t)IPAD * NPAD);  // next head, chunk 0

            // ---- S^T = relu(Zb_chunk . ZQ^T): D[m][n], b64-packed stores ----
#pragma unroll
            for (int mt = 0; mt < 2; mt++) {
                f32x4 st0 = (f32x4){0.f,0.f,0.f,0.f}, st1 = st0;
                const bf16* zr = &zbS[p][mt * 16 + l16][0];
#pragma unroll
                for (int kc = 0; kc < 8; kc++) {
                    bf16x8 az = *(const bf16x8*)(zr + (((kc * 4 + quad) ^ xs) * 8));
                    st0 = mfma16(az, zqa[0][kc], st0);
                    st1 = mfma16(az, zqa[1][kc], st1);
                }
                // lane holds S[n=l16+16ns][m = m0+mt*16+quad*4+r]
                bf16x4 p0, p1;
#pragma unroll
                for (int r = 0; r < 4; r++) {
                    p0[r] = (bf16)(st0[r] > 0.f ? st0[r] : 0.f);
                    p1[r] = (bf16)(st1[r] > 0.f ? st1[r] : 0.f);
                }
                *(bf16x4*)(&sl[wave][l16][mt * 16 + quad * 4])      = p0;
                *(bf16x4*)(&sl[wave][16 + l16][mt * 16 + quad * 4]) = p1;
            }
            bf16x8 sfrag[2];
#pragma unroll
            for (int ns = 0; ns < 2; ns++)
                sfrag[ns] = *(const bf16x8*)(&sl[wave][ns * 16 + l16][quad * 8]);

            // ---- acc += S . KT_chunk^T ----
#pragma unroll
            for (int it = 0; it < 17; it++) {
                const bf16* kr = &ktS[p][it * 16 + l16][0];
                bf16x8 bk = *(const bf16x8*)(kr + ((quad ^ kf) * 8));
                acc[0][it] = mfma16(sfrag[0], bk, acc[0][it]);
                acc[1][it] = mfma16(sfrag[1], bk, acc[1][it]);
            }
            __syncthreads();
        }
    }

    // ---- epilogue: Z += acc / N ----
    const float inv = 1.0f / (float)N_;
#pragma unroll
    for (int ns = 0; ns < 2; ns++)
#pragma unroll
        for (int it = 0; it < 17; it++)
#pragma unroll
            for (int r = 0; r < 4; r++) {
                int n = n0w + ns * 16 + quad * 4 + r;
                int i = it * 16 + l16;
                if (n < NP1 && i < DP1)
                    Z[((size_t)b * NP1 + n) * DP1 + i] += acc[ns][it][r] * inv;
            }
}

// ---------------------------------------------------------------------------
extern "C" void kernel_launch(void* const* d_in, const int* in_sizes, int n_in,
                              void* d_out, int out_size, void* d_ws, size_t ws_size,
                              hipStream_t stream) {
    const float* Zin = (const float*)d_in[0];
    const float* ap  = (const float*)d_in[1];
    float* Z = (float*)d_out;

    char* ws = (char*)d_ws;
    const size_t sz_Zb = (size_t)B_ * NROWS * D_ * sizeof(bf16);
    const size_t sz_KT = (size_t)B_ * H_ * IPAD * NPAD * sizeof(bf16);
    const size_t sz_P  = (size_t)L_ * H_ * D_ * D_ * sizeof(bf16);
    bf16* Zb = (bf16*)ws;
    bf16* KT = (bf16*)(ws + sz_Zb);
    bf16* Pb = (bf16*)(ws + sz_Zb + sz_KT);
    bf16* Qt = (bf16*)(ws + sz_Zb + sz_KT + sz_P);

    hipMemcpyAsync(Z, Zin, (size_t)B_ * NP1 * DP1 * sizeof(float),
                   hipMemcpyDeviceToDevice, stream);

    k_prep_pq<<<dim3((L_ * H_ * D_ * D_) / 256), 256, 0, stream>>>(ap, Pb, Qt);
    k_kt_pad<<<dim3((NPAD + 255) / 256, B_ * H_), 256, 0, stream>>>(KT);

    for (int l = 0; l < L_; l++) {
        k_z2b<<<dim3(NROWS, B_), 256, 0, stream>>>(Z, Zb);
        k_kt<<<dim3(NPAD / 64, D_ / 64, B_ * H_), 256, 0, stream>>>(Zb, Pb, KT, l);
        k_kt_extra<<<dim3((NPAD + 255) / 256, B_), 256, 0, stream>>>(Z, KT);
        k_attn<<<dim3(9 * B_), 256, 0, stream>>>(Zb, KT, Qt, Z, l);
    }
}